// Round 1
// baseline (185.617 us; speedup 1.0000x reference)
//
#include <hip/hip_runtime.h>

namespace {

constexpr int LMAX = 10;
constexpr int NR   = (LMAX + 1) * (LMAX + 2) / 2;  // 66 real accumulators
constexpr int NI   = (LMAX + 1) * LMAX / 2;        // 55 imag accumulators
constexpr int NACC = NR + NI;                      // 121
constexpr double PI_D = 3.14159265358979323846;

constexpr double dfact(int n) {
    double r = 1.0;
    for (int i = 2; i <= n; ++i) r *= (double)i;
    return r;
}

constexpr double csqrt(double x) {
    if (x <= 0.0) return 0.0;
    double g = x > 1.0 ? x : 1.0;
    for (int i = 0; i < 100; ++i) g = 0.5 * (g + x / g);
    return g;
}

constexpr double FACT[LMAX + 1] = {1., 1., 2., 6., 24., 120., 720., 5040., 40320., 362880., 3628800.};

struct Tables {
    int   map[NACC];
    float scl[NACC];
};

constexpr Tables make_tables() {
    Tables t{};
    // Real accumulators: acc[l*(l+1)/2 + m] = sum(shr * x0 * r^l * mask)
    for (int l = 0; l <= LMAX; ++l) {
        for (int m = 0; m <= l; ++m) {
            const int k = l * (l + 1) / 2 + m;
            const double scale = csqrt(dfact(l + m) * dfact(l - m)) * csqrt((2 * l + 1) / (4.0 * PI_D));
            if (m == 0) {
                t.map[k] = l * l + l;          // clms[i], i = l^2 + l
                t.scl[k] = (float)scale;
            } else {
                const double f = csqrt(2.0) * ((m & 1) ? -1.0 : 1.0);
                t.map[k] = l * l + l + m;      // clms[i + 2m] = f * clm_r
                t.scl[k] = (float)(f * scale);
            }
        }
    }
    // Imag accumulators: acc[NR + l*(l-1)/2 + (m-1)] = sum(shi * x0 * r^l * mask)
    for (int l = 1; l <= LMAX; ++l) {
        for (int m = 1; m <= l; ++m) {
            const int k = NR + l * (l - 1) / 2 + (m - 1);
            const double scale = csqrt(dfact(l + m) * dfact(l - m)) * csqrt((2 * l + 1) / (4.0 * PI_D));
            const double f = csqrt(2.0) * ((m & 1) ? -1.0 : 1.0);
            t.map[k] = l * l + l - m;          // clms[i] = f * clm_i
            t.scl[k] = (float)(f * scale);
        }
    }
    return t;
}

__constant__ Tables c_tab = make_tables();

}  // namespace

// One monolithic pass: each thread accumulates all 121 coefficients over its
// grid-stride share of points, then wave shuffle-reduce -> LDS cross-wave
// combine -> one atomicAdd per block per output.
//
// Algebra note: reference's z2 = (x/2,-y/2) = -conj(z1) with z1 = (-x/2,-y/2).
// Sign flips are exact in fp, so z2^q = ((-1)^q z1r[q], (-1)^(q+1) z1i[q])
// bitwise. Hence:
//   zreal = z1r[p]^2 - z2i[q]^2 = z1r[p]^2 - z1i[q]^2            (sign-free)
//   zimag = z1r[p]*z2i[q] + z1i[p]*z2r[q]
//         = (-1)^q * (z1i[p]*z1r[q] - z1r[p]*z1i[q])             (sign -> const)
__global__ __launch_bounds__(256) void sht_kernel(const float* __restrict__ pos,
                                                  float* __restrict__ out, int n) {
    float acc[NACC];
#pragma unroll
    for (int k = 0; k < NACC; ++k) acc[k] = 0.f;

    const int tid    = blockIdx.x * blockDim.x + threadIdx.x;
    const int stride = gridDim.x * blockDim.x;

    for (int i = tid; i < n; i += stride) {
        const float x  = pos[3 * i + 0];
        const float y  = pos[3 * i + 1];
        const float x0 = pos[3 * i + 2];

        const float nrm = sqrtf(x * x + y * y + x0 * x0);
        const float w0  = (nrm > 0.f) ? x0 : 0.f;  // x0 * mask (all terms ~ x0)

        // Powers of z1 = (-x/2, -y/2), repeated complex multiply (matches ref)
        float zr[LMAX + 1], zi[LMAX + 1];
        zr[0] = 1.f;
        zi[0] = 0.f;
        const float ar = -0.5f * x, ai = -0.5f * y;
#pragma unroll
        for (int p = 1; p <= LMAX; ++p) {
            zr[p] = ar * zr[p - 1] - ai * zi[p - 1];
            zi[p] = ar * zi[p - 1] + ai * zr[p - 1];
        }
        float sr[LMAX + 1], si[LMAX + 1];
#pragma unroll
        for (int p = 0; p <= LMAX; ++p) {
            sr[p] = zr[p] * zr[p];
            si[p] = zi[p] * zi[p];
        }

        float rl = 1.f;  // nrm^l
#pragma unroll
        for (int l = 0; l <= LMAX; ++l) {
            if (l > 0) rl *= nrm;
            const float wrl = w0 * rl;
#pragma unroll
            for (int m = 0; m <= l; ++m) {
                float shr = 0.f;
                float shi = 0.f;
#pragma unroll
                for (int p = m; 2 * p <= l + m; ++p) {
                    const int q = p - m;
                    const int s = l - 2 * p + m;
                    const float cr = (float)(1.0 / (FACT[p] * FACT[q] * FACT[s]));
                    shr += (sr[p] - si[q]) * cr;
                    if (m > 0) {
                        const float ci = (q & 1) ? -cr : cr;  // (-1)^q folded
                        shi += (zi[p] * zr[q] - zr[p] * zi[q]) * ci;
                    }
                }
                acc[l * (l + 1) / 2 + m] += shr * wrl;
                if (m > 0) acc[NR + l * (l - 1) / 2 + (m - 1)] += shi * wrl;
            }
        }
    }

    // Wave (64-lane) shuffle reduction, then cross-wave via LDS.
    __shared__ float red[4][NACC];
    const int lane = threadIdx.x & 63;
    const int wav  = threadIdx.x >> 6;
#pragma unroll
    for (int k = 0; k < NACC; ++k) {
        float v = acc[k];
#pragma unroll
        for (int off = 32; off > 0; off >>= 1) v += __shfl_down(v, off, 64);
        if (lane == 0) red[wav][k] = v;
    }
    __syncthreads();
    if ((int)threadIdx.x < NACC) {
        const int k   = threadIdx.x;
        const float v = red[0][k] + red[1][k] + red[2][k] + red[3][k];
        atomicAdd(&out[c_tab.map[k]], v * c_tab.scl[k]);
    }
}

extern "C" void kernel_launch(void* const* d_in, const int* in_sizes, int n_in,
                              void* d_out, int out_size, void* d_ws, size_t ws_size,
                              hipStream_t stream) {
    const float* pos = (const float*)d_in[0];
    float* out       = (float*)d_out;
    const int n      = in_sizes[0] / 3;  // (N,3) flat -> N points

    // d_out is poisoned before every launch; we accumulate via atomics.
    hipMemsetAsync(d_out, 0, (size_t)out_size * sizeof(float), stream);

    const int threads = 256;
    const int blocks  = 512;  // 2048 waves = 2 waves/SIMD at ~200 VGPR; ~15 pts/thread
    sht_kernel<<<blocks, threads, 0, stream>>>(pos, out, n);
}

// Round 2
// 136.573 us; speedup vs baseline: 1.3591x; 1.3591x over previous
//
#include <hip/hip_runtime.h>

namespace {

constexpr int LMAX  = 10;
constexpr int NPART = 4;
// Greedy-balanced partition of l into 4 parts by inner-term count:
// P0{10,3}=42 terms, P1{9,4}=39, P2{8,5,1}=41, P3{7,6,2,0}=41
constexpr int PART_OF_L[LMAX + 1] = {3, 2, 3, 0, 1, 2, 3, 3, 2, 1, 0};
constexpr double PI_D = 3.14159265358979323846;

constexpr double dfact(int n) {
    double r = 1.0;
    for (int i = 2; i <= n; ++i) r *= (double)i;
    return r;
}

constexpr double csqrt(double x) {
    if (x <= 0.0) return 0.0;
    double g = x > 1.0 ? x : 1.0;
    for (int i = 0; i < 100; ++i) g = 0.5 * (g + x / g);
    return g;
}

constexpr double FACT[LMAX + 1] = {1., 1., 2., 6., 24., 120., 720., 5040., 40320., 362880., 3628800.};

// ---- per-part accumulator slot layout -------------------------------------
// For each l in the part (ascending): (l+1) real slots (m=0..l), then l imag
// slots (m=1..l).
constexpr int slot_base(int part, int l) {
    int c = 0;
    for (int ll = 0; ll < l; ++ll)
        if (PART_OF_L[ll] == part) c += 2 * ll + 1;
    return c;
}
constexpr int nacc_part(int part) {
    int c = 0;
    for (int l = 0; l <= LMAX; ++l)
        if (PART_OF_L[l] == part) c += 2 * l + 1;
    return c;
}
constexpr int part_lmax(int part) {
    int mx = 0;
    for (int l = 0; l <= LMAX; ++l)
        if (PART_OF_L[l] == part) mx = l;
    return mx;
}
constexpr int slot_r(int part, int l, int m) { return slot_base(part, l) + m; }
constexpr int slot_i(int part, int l, int m) { return slot_base(part, l) + (l + 1) + (m - 1); }

constexpr int MAXNA = 34;  // max nacc_part over parts (P3: 1+5+13+15 = 34)

struct Tables {
    int   map[NPART][MAXNA];
    float scl[NPART][MAXNA];
};

constexpr Tables make_tables() {
    Tables t{};
    for (int part = 0; part < NPART; ++part) {
        for (int l = 0; l <= LMAX; ++l) {
            if (PART_OF_L[l] != part) continue;
            for (int m = 0; m <= l; ++m) {
                const int k = slot_r(part, l, m);
                const double scale =
                    csqrt(dfact(l + m) * dfact(l - m)) * csqrt((2 * l + 1) / (4.0 * PI_D));
                if (m == 0) {
                    t.map[part][k] = l * l + l;
                    t.scl[part][k] = (float)scale;
                } else {
                    const double f = csqrt(2.0) * ((m & 1) ? -1.0 : 1.0);
                    t.map[part][k] = l * l + l + m;
                    t.scl[part][k] = (float)(f * scale);
                }
            }
            for (int m = 1; m <= l; ++m) {
                const int k = slot_i(part, l, m);
                const double scale =
                    csqrt(dfact(l + m) * dfact(l - m)) * csqrt((2 * l + 1) / (4.0 * PI_D));
                const double f = csqrt(2.0) * ((m & 1) ? -1.0 : 1.0);
                t.map[part][k] = l * l + l - m;
                t.scl[part][k] = (float)(f * scale);
            }
        }
    }
    return t;
}

__constant__ Tables c_tab = make_tables();

}  // namespace

// Algebra (exact in fp): reference's z2 = (x/2,-y/2) = -conj(z1), z1 = (-x/2,-y/2).
//   zreal = z1r[p]^2 - z1i[q]^2
//   zimag = (-1)^q * (z1i[p]*z1r[q] - z1r[p]*z1i[q])
// so only one power table is needed and all signs fold into constants.
//
// 4-way l-split: each part keeps <=34 accumulators (vs 121 monolithic), freeing
// ~60 VGPRs of temporaries for ILP and lifting occupancy to ~5 waves/SIMD.
template <int PART>
__device__ __forceinline__ void sht_part(const float* __restrict__ pos,
                                         float* __restrict__ out, int n, int nblk) {
    constexpr int NA = nacc_part(PART);
    constexpr int PL = part_lmax(PART);

    float acc[NA];
#pragma unroll
    for (int k = 0; k < NA; ++k) acc[k] = 0.f;

    const int bid    = (int)(blockIdx.x >> 2);
    const int tid    = bid * 256 + (int)threadIdx.x;
    const int stride = nblk * 256;

    int   i = tid;
    float x = 0.f, y = 0.f, z0 = 0.f;
    if (i < n) {
        x  = pos[3 * i + 0];
        y  = pos[3 * i + 1];
        z0 = pos[3 * i + 2];
    }

    while (i < n) {
        // software-pipelined prefetch of the next point
        const int inext = i + stride;
        float     px = 0.f, py = 0.f, pz = 0.f;
        if (inext < n) {
            px = pos[3 * inext + 0];
            py = pos[3 * inext + 1];
            pz = pos[3 * inext + 2];
        }

        const float nrm = sqrtf(x * x + y * y + z0 * z0);
        const float w0  = (nrm > 0.f) ? z0 : 0.f;  // x0 * mask

        // Powers of z1 = (-x/2, -y/2), repeated complex multiply (matches ref)
        float zr[PL + 1], zi[PL + 1];
        zr[0] = 1.f;
        zi[0] = 0.f;
        const float ar = -0.5f * x, ai = -0.5f * y;
#pragma unroll
        for (int p = 1; p <= PL; ++p) {
            zr[p] = ar * zr[p - 1] - ai * zi[p - 1];
            zi[p] = ar * zi[p - 1] + ai * zr[p - 1];
        }
        float sr[PL + 1], si[PL + 1];
#pragma unroll
        for (int p = 0; p <= PL; ++p) {
            sr[p] = zr[p] * zr[p];
            si[p] = zi[p] * zi[p];
        }
        float rp[PL + 1];
        rp[0] = 1.f;
#pragma unroll
        for (int l = 1; l <= PL; ++l) rp[l] = rp[l - 1] * nrm;

#pragma unroll
        for (int l = 0; l <= LMAX; ++l) {
            if (PART_OF_L[l] != PART) continue;  // compile-time eliminated
            const float wrl = w0 * rp[l];
#pragma unroll
            for (int m = 0; m <= l; ++m) {
                float shr = 0.f;
                float shi = 0.f;
#pragma unroll
                for (int p = m; 2 * p <= l + m; ++p) {
                    const int   q  = p - m;
                    const float cr = (float)(1.0 / (FACT[p] * FACT[q] * FACT[l - 2 * p + m]));
                    shr += (sr[p] - si[q]) * cr;
                    if (m > 0) {
                        const float ci = (q & 1) ? -cr : cr;  // (-1)^q folded
                        shi += (zi[p] * zr[q] - zr[p] * zi[q]) * ci;
                    }
                }
                acc[slot_r(PART, l, m)] += shr * wrl;
                if (m > 0) acc[slot_i(PART, l, m)] += shi * wrl;
            }
        }

        i  = inext;
        x  = px;
        y  = py;
        z0 = pz;
    }

    // Wave (64-lane) shuffle reduction, then cross-wave via LDS.
    __shared__ float red[4][NA];
    const int lane = threadIdx.x & 63;
    const int wav  = threadIdx.x >> 6;
#pragma unroll
    for (int k = 0; k < NA; ++k) {
        float v = acc[k];
#pragma unroll
        for (int off = 32; off > 0; off >>= 1) v += __shfl_down(v, off, 64);
        if (lane == 0) red[wav][k] = v;
    }
    __syncthreads();
    if ((int)threadIdx.x < NA) {
        const int   k = (int)threadIdx.x;
        const float v = red[0][k] + red[1][k] + red[2][k] + red[3][k];
        atomicAdd(&out[c_tab.map[PART][k]], v * c_tab.scl[PART][k]);
    }
}

__global__ __launch_bounds__(256) void sht_kernel(const float* __restrict__ pos,
                                                  float* __restrict__ out, int n, int nblk) {
    // part = blockIdx & 3: under round-robin block->CU dispatch (stride 256,
    // 256 == 0 mod 4), all resident blocks on one CU share a part -> I$ locality.
    switch (blockIdx.x & 3) {
        case 0: sht_part<0>(pos, out, n, nblk); break;
        case 1: sht_part<1>(pos, out, n, nblk); break;
        case 2: sht_part<2>(pos, out, n, nblk); break;
        default: sht_part<3>(pos, out, n, nblk); break;
    }
}

extern "C" void kernel_launch(void* const* d_in, const int* in_sizes, int n_in,
                              void* d_out, int out_size, void* d_ws, size_t ws_size,
                              hipStream_t stream) {
    const float* pos = (const float*)d_in[0];
    float* out       = (float*)d_out;
    const int n      = in_sizes[0] / 3;  // (N,3) flat -> N points

    // d_out is poisoned before every launch; we accumulate via atomics.
    hipMemsetAsync(d_out, 0, (size_t)out_size * sizeof(float), stream);

    const int threads       = 256;
    const int nblk_per_part = 512;                 // ~15 pts/thread per part
    const int blocks        = NPART * nblk_per_part;  // 2048
    sht_kernel<<<blocks, threads, 0, stream>>>(pos, out, n, nblk_per_part);
}